// Round 5
// baseline (2529.953 us; speedup 1.0000x reference)
//
#include <hip/hip_runtime.h>
#include <stdint.h>

#define N_NODES 100000
#define D_FEAT  128
#define RSH     6                                 // log2(RPB)
#define RPB     64                                // rows per bucket
#define NBUCK   ((N_NODES + RPB - 1) / RPB)       // 1563
#define CAPF    2304                              // mean 2048 + 5.6 sigma
#define KMAX    ((CAPF + 255) / 256)              // 9 records/thread in spmm load
#define NSH     13                                // column shards (col>>13), 2.1MB bf16 slice
#define OCAP    8192                              // overflow list capacity
#define SC_THR  1024
#define SC_EPT  8
#define SC_TILE (SC_THR * SC_EPT)                 // 8192 edges per scatter WG
#define COLMASK 0x1FFFF

// ---------- Phase 1: single-pass batched scatter into fixed-capacity slabs ----------
// (byte-identical to rounds 2/3/4 — isolate the spmm change)
__global__ __launch_bounds__(SC_THR) void scatter_fixed_kernel(
    const int* __restrict__ row, const int* __restrict__ col,
    const float* __restrict__ val, int* __restrict__ cursor,
    int2* __restrict__ rec, int4* __restrict__ oflow, int* __restrict__ ocnt, int n,
    const uint64_t* __restrict__ embin, uint32_t* __restrict__ embbf, int do_conv)
{
    __shared__ int cnt[NBUCK];                    // 6.25 KB
    __shared__ int base[NBUCK];                   // 6.25 KB
    const int tid = threadIdx.x;

    // fused conversion: fp32 pairs -> packed bf16 (RNE), streaming nt loads
    if (do_conv) {
        const int n2 = N_NODES * (D_FEAT / 2);
        const int stride = (int)gridDim.x * SC_THR;
        for (int i = (int)blockIdx.x * SC_THR + tid; i < n2; i += stride) {
            uint64_t u = __builtin_nontemporal_load(embin + i);
            uint32_t bx = (uint32_t)u, by = (uint32_t)(u >> 32);
            bx = (bx + 0x7FFFu + ((bx >> 16) & 1u)) >> 16;
            by = (by + 0x7FFFu + ((by >> 16) & 1u)) >> 16;
            embbf[i] = bx | (by << 16);
        }
    }

    const int e0 = (int)blockIdx.x * SC_TILE + tid * SC_EPT; // 8 consecutive edges/thread

    for (int i = tid; i < NBUCK; i += SC_THR) cnt[i] = 0;
    __syncthreads();

    int   r[SC_EPT], c[SC_EPT];
    float v[SC_EPT];
    if (e0 + SC_EPT <= n) {
        const int4* rp = (const int4*)(row + e0);
        const int4* cp = (const int4*)(col + e0);
        const float4* vp = (const float4*)(val + e0);
        #pragma unroll
        for (int q = 0; q < SC_EPT / 4; q++) {
            int4 rr = rp[q]; int4 cc = cp[q]; float4 vv = vp[q];
            r[q*4+0]=rr.x; r[q*4+1]=rr.y; r[q*4+2]=rr.z; r[q*4+3]=rr.w;
            c[q*4+0]=cc.x; c[q*4+1]=cc.y; c[q*4+2]=cc.z; c[q*4+3]=cc.w;
            v[q*4+0]=vv.x; v[q*4+1]=vv.y; v[q*4+2]=vv.z; v[q*4+3]=vv.w;
        }
    } else {
        #pragma unroll
        for (int k = 0; k < SC_EPT; k++) {
            int e = e0 + k;
            if (e < n) { r[k] = row[e]; c[k] = col[e]; v[k] = val[e]; }
            else       { r[k] = -1; }
        }
    }

    int rk[SC_EPT];
    #pragma unroll
    for (int k = 0; k < SC_EPT; k++)
        if (r[k] >= 0) rk[k] = atomicAdd(&cnt[r[k] >> RSH], 1);
    __syncthreads();

    for (int i = tid; i < NBUCK; i += SC_THR) {
        int cc = cnt[i];
        if (cc) base[i] = atomicAdd(&cursor[i], cc);
    }
    __syncthreads();

    #pragma unroll
    for (int k = 0; k < SC_EPT; k++) {
        if (r[k] >= 0) {
            int bk  = r[k] >> RSH;
            int pos = base[bk] + rk[k];
            if (pos < CAPF) {
                rec[(size_t)bk * CAPF + pos] =
                    make_int2(((r[k] & (RPB - 1)) << 17) | c[k], __float_as_int(v[k]));
            } else {
                int op = atomicAdd(ocnt, 1);
                if (op < OCAP) oflow[op] = make_int4(r[k], c[k], __float_as_int(v[k]), 0);
            }
        }
    }
}

// ---------- Phase 2: shard-sorted SpMM with LDS accumulators ----------
// Same structure as round 4 EXCEPT: LDS accumulation via unsafeAtomicAdd ->
// native fire-and-forget ds_add_f32 (round 4's atomicAdd lowered to a CAS
// loop: two dependent ~120cy LDS round-trips per add -> 2.4ms, VALUBusy 2.5%).
// Plus a per-shard __syncthreads() to keep the WG's waves in shard lockstep
// (restores the 2.1MB-slice L2 residency = round 3's FETCH win).
template <bool BF16>
__global__ __launch_bounds__(256, 3) void spmm_fixed_kernel(const int* __restrict__ fill,
                                                            const int2* __restrict__ rec,
                                                            const void* __restrict__ emb,
                                                            float* __restrict__ out)
{
    __shared__ int2  buf[CAPF];                   // 18.4 KB
    __shared__ float accx[RPB * 64];              // 16 KB
    __shared__ float accy[RPB * 64];              // 16 KB
    __shared__ int   cnt[NSH];
    __shared__ int   start[NSH + 1];

    const int tid  = threadIdx.x;
    const int lane = tid & 63;
    const int wv   = tid >> 6;                    // 0..3
    const int b    = blockIdx.x;
    const int m    = min(fill[b], CAPF);
    const uint64_t* __restrict__ rec8 = (const uint64_t*)rec + (size_t)b * CAPF;
    const uint32_t* __restrict__ embu = (const uint32_t*)emb;
    const float2*   __restrict__ emb2 = (const float2*)emb;

    if (tid < NSH) cnt[tid] = 0;
    for (int i = tid; i < RPB * 64; i += 256) { accx[i] = 0.f; accy[i] = 0.f; }
    __syncthreads();

    // rank by shard (13 keys)
    int2 rc[KMAX];
    int  rk[KMAX];
    int  ky[KMAX];
    #pragma unroll
    for (int k = 0; k < KMAX; k++) {
        int i = k * 256 + tid;
        rk[k] = -1;
        if (i < m) {
            uint64_t u = __builtin_nontemporal_load(rec8 + i);   // streamed once
            rc[k].x = (int)(uint32_t)u;
            rc[k].y = (int)(uint32_t)(u >> 32);
            ky[k] = (int)(((uint32_t)rc[k].x & COLMASK) >> 13);  // 0..12
            rk[k] = atomicAdd(&cnt[ky[k]], 1);
        }
    }
    __syncthreads();
    if (tid == 0) {                               // tiny serial scan, 13 elems
        int acc = 0;
        #pragma unroll
        for (int s = 0; s < NSH; s++) { start[s] = acc; acc += cnt[s]; }
        start[NSH] = acc;
    }
    __syncthreads();
    #pragma unroll
    for (int k = 0; k < KMAX; k++)
        if (rk[k] >= 0) buf[start[ky[k]] + rk[k]] = rc[k];
    __syncthreads();

    // shard-major sweep; wave takes a contiguous quarter of each segment
    for (int s = 0; s < NSH; s++) {
        const int s0   = start[s];
        const int c0   = cnt[s];
        const int qlen = (c0 + 3) >> 2;
        const int a    = s0 + wv * qlen;
        const int bnd  = min(s0 + c0, a + qlen);
        int j = a;
        for (; j + 16 <= bnd; j += 16) {          // flat 16-deep gather batch
            uint32_t u[16]; float vv[16]; int rw[16]; float2 m2[16];
            #pragma unroll
            for (int q = 0; q < 16; q++) {
                int2 e = buf[j + q];              // wave-uniform -> broadcast
                u[q]  = (((uint32_t)e.x & COLMASK) << 6) | (uint32_t)lane;
                rw[q] = (int)((uint32_t)e.x >> 17);
                vv[q] = __int_as_float(e.y);
            }
            #pragma unroll
            for (int q = 0; q < 16; q++) {
                if (BF16) u[q] = embu[u[q]]; else m2[q] = emb2[u[q]];
            }
            #pragma unroll
            for (int q = 0; q < 16; q++) {
                float tx, ty;
                if (BF16) {
                    tx = vv[q] * __uint_as_float(u[q] << 16);
                    ty = vv[q] * __uint_as_float(u[q] & 0xFFFF0000u);
                } else {
                    tx = vv[q] * m2[q].x; ty = vv[q] * m2[q].y;
                }
                int ad = (rw[q] << 6) | lane;
                unsafeAtomicAdd(&accx[ad], tx);   // ds_add_f32, fire-and-forget
                unsafeAtomicAdd(&accy[ad], ty);
            }
        }
        for (; j + 4 <= bnd; j += 4) {
            uint32_t u[4]; float vv[4]; int rw[4]; float2 m2[4];
            #pragma unroll
            for (int q = 0; q < 4; q++) {
                int2 e = buf[j + q];
                u[q]  = (((uint32_t)e.x & COLMASK) << 6) | (uint32_t)lane;
                rw[q] = (int)((uint32_t)e.x >> 17);
                vv[q] = __int_as_float(e.y);
            }
            #pragma unroll
            for (int q = 0; q < 4; q++) {
                if (BF16) u[q] = embu[u[q]]; else m2[q] = emb2[u[q]];
            }
            #pragma unroll
            for (int q = 0; q < 4; q++) {
                float tx, ty;
                if (BF16) {
                    tx = vv[q] * __uint_as_float(u[q] << 16);
                    ty = vv[q] * __uint_as_float(u[q] & 0xFFFF0000u);
                } else {
                    tx = vv[q] * m2[q].x; ty = vv[q] * m2[q].y;
                }
                int ad = (rw[q] << 6) | lane;
                unsafeAtomicAdd(&accx[ad], tx);
                unsafeAtomicAdd(&accy[ad], ty);
            }
        }
        for (; j < bnd; j++) {
            int2 e = buf[j];
            uint32_t off = (((uint32_t)e.x & COLMASK) << 6) | (uint32_t)lane;
            int rw = (int)((uint32_t)e.x >> 17);
            float vj = __int_as_float(e.y);
            float tx, ty;
            if (BF16) {
                uint32_t w = embu[off];
                tx = vj * __uint_as_float(w << 16);
                ty = vj * __uint_as_float(w & 0xFFFF0000u);
            } else {
                float2 mm = emb2[off];
                tx = vj * mm.x; ty = vj * mm.y;
            }
            int ad = (rw << 6) | lane;
            unsafeAtomicAdd(&accx[ad], tx);
            unsafeAtomicAdd(&accy[ad], ty);
        }
        __syncthreads();                          // intra-WG shard lockstep (L2 residency)
    }

    // writeout: wave wv owns rows wv*16..wv*16+15
    #pragma unroll
    for (int p = 0; p < 16; p++) {
        const int rl   = wv * 16 + p;
        const int grow = b * RPB + rl;            // NBUCK*RPB = 100032 > N_NODES
        if (grow < N_NODES) {
            int ad = (rl << 6) | lane;
            uint64_t w = (uint64_t)__float_as_uint(accx[ad]) |
                         ((uint64_t)__float_as_uint(accy[ad]) << 32);
            __builtin_nontemporal_store(w, (uint64_t*)out + (size_t)grow * 64 + lane);
        }
    }
}

// ---------- Phase 3: overflow fixup (statistically ~0 edges) ----------
__global__ __launch_bounds__(256) void oflow_kernel(const int4* __restrict__ oflow,
                                                    const int* __restrict__ ocnt,
                                                    const float* __restrict__ embeds,
                                                    float* __restrict__ out) {
    const int nof  = min(*ocnt, OCAP);
    const int lane = threadIdx.x & 63;
    const int w    = ((int)blockIdx.x * 256 + threadIdx.x) >> 6;
    const int nw   = ((int)gridDim.x * 256) >> 6;
    for (int i = w; i < nof; i += nw) {
        int4 e = oflow[i];
        const float2* src = (const float2*)(embeds + (size_t)e.y * D_FEAT);
        float2 mm = src[lane];
        float vv = __int_as_float(e.z);
        float* dst = out + (size_t)e.x * D_FEAT + (lane << 1);
        unsafeAtomicAdd(dst,     vv * mm.x);
        unsafeAtomicAdd(dst + 1, vv * mm.y);
    }
}

// ---------- Last-resort fallback (ws too small): atomic scatter ----------
__global__ __launch_bounds__(256) void spmm_atomic_kernel(
    const int* __restrict__ edge_row, const int* __restrict__ edge_col,
    const float* __restrict__ edge_val, const float* __restrict__ embeds,
    float* __restrict__ out, int n_edges)
{
    const int lane    = threadIdx.x & 63;
    const int wave_id = ((int)blockIdx.x * blockDim.x + threadIdx.x) >> 6;
    const int n_waves = ((int)gridDim.x * blockDim.x) >> 6;
    for (int e = wave_id; e < n_edges; e += n_waves) {
        const int   r = edge_row[e];
        const int   c = edge_col[e];
        const float vv = edge_val[e];
        const float2* src = (const float2*)(embeds + (size_t)c * D_FEAT);
        float2 mm = src[lane];
        float* dst = out + (size_t)r * D_FEAT + (lane << 1);
        unsafeAtomicAdd(dst,     vv * mm.x);
        unsafeAtomicAdd(dst + 1, vv * mm.y);
    }
}

static inline size_t align256(size_t x) { return (x + 255) & ~(size_t)255; }

extern "C" void kernel_launch(void* const* d_in, const int* in_sizes, int n_in,
                              void* d_out, int out_size, void* d_ws, size_t ws_size,
                              hipStream_t stream) {
    const int*   edge_row = (const int*)d_in[0];
    const int*   edge_col = (const int*)d_in[1];
    const float* edge_val = (const float*)d_in[2];
    const float* embeds   = (const float*)d_in[3];
    float*       out      = (float*)d_out;

    const int n_edges = in_sizes[0];

    size_t off = 0;
    size_t o_cursor = off; off = align256(off + (size_t)(NBUCK + 1) * 4);  // cursor + ocnt
    size_t o_oflow  = off; off = align256(off + (size_t)OCAP * 16);
    size_t o_rec    = off; off = align256(off + (size_t)NBUCK * CAPF * 8); // 28.8 MB
    const size_t need_fp32 = off;
    size_t o_emb    = off; off = align256(off + (size_t)N_NODES * 64 * 4); // 25.6 MB
    const size_t need_bf16 = off;

    if (ws_size < need_fp32) {
        hipMemsetAsync(out, 0, (size_t)out_size * sizeof(float), stream);
        spmm_atomic_kernel<<<dim3(4096), dim3(256), 0, stream>>>(
            edge_row, edge_col, edge_val, embeds, out, n_edges);
        return;
    }

    char* ws = (char*)d_ws;
    int*      cursor = (int*)(ws + o_cursor);     // [NBUCK] fill counts; +1 = ocnt
    int*      ocnt   = cursor + NBUCK;
    int4*     oflow  = (int4*)(ws + o_oflow);
    int2*     rec    = (int2*)(ws + o_rec);
    uint32_t* embbf  = (uint32_t*)(ws + o_emb);

    const bool use_bf16 = (ws_size >= need_bf16);

    hipMemsetAsync(cursor, 0, (size_t)(NBUCK + 1) * 4, stream);
    scatter_fixed_kernel<<<dim3((n_edges + SC_TILE - 1) / SC_TILE), dim3(SC_THR), 0, stream>>>(
        edge_row, edge_col, edge_val, cursor, rec, oflow, ocnt, n_edges,
        (const uint64_t*)embeds, embbf, use_bf16 ? 1 : 0);
    if (use_bf16)
        spmm_fixed_kernel<true><<<dim3(NBUCK), dim3(256), 0, stream>>>(cursor, rec, embbf, out);
    else
        spmm_fixed_kernel<false><<<dim3(NBUCK), dim3(256), 0, stream>>>(cursor, rec, embeds, out);
    oflow_kernel<<<dim3(16), dim3(256), 0, stream>>>(oflow, ocnt, embeds, out);
}

// Round 6
// 504.906 us; speedup vs baseline: 5.0107x; 5.0107x over previous
//
#include <hip/hip_runtime.h>
#include <stdint.h>

#define N_NODES 100000
#define D_FEAT  128
#define RSH     6                                 // log2(RPB)
#define RPB     64                                // rows per bucket
#define NBUCK   ((N_NODES + RPB - 1) / RPB)       // 1563
#define CAPF    2304                              // mean 2048 + 5.6 sigma
#define KMAX    ((CAPF + 255) / 256)              // 9 records/thread in spmm load
#define NSH     13                                // column shards (col>>13), 2.1MB bf16 slice
#define KEYS    (NSH * RPB)                       // 832 sort keys
#define OCAP    8192                              // overflow list capacity
#define SC_THR  1024
#define SC_EPT  8
#define SC_TILE (SC_THR * SC_EPT)                 // 8192 edges per scatter WG
#define COLMASK 0x1FFFF

// ---------- Phase 1: single-pass batched scatter into fixed-capacity slabs ----------
// (byte-identical to rounds 2-5)
__global__ __launch_bounds__(SC_THR) void scatter_fixed_kernel(
    const int* __restrict__ row, const int* __restrict__ col,
    const float* __restrict__ val, int* __restrict__ cursor,
    int2* __restrict__ rec, int4* __restrict__ oflow, int* __restrict__ ocnt, int n,
    const uint64_t* __restrict__ embin, uint32_t* __restrict__ embbf, int do_conv)
{
    __shared__ int cnt[NBUCK];                    // 6.25 KB
    __shared__ int base[NBUCK];                   // 6.25 KB
    const int tid = threadIdx.x;

    if (do_conv) {
        const int n2 = N_NODES * (D_FEAT / 2);
        const int stride = (int)gridDim.x * SC_THR;
        for (int i = (int)blockIdx.x * SC_THR + tid; i < n2; i += stride) {
            uint64_t u = __builtin_nontemporal_load(embin + i);
            uint32_t bx = (uint32_t)u, by = (uint32_t)(u >> 32);
            bx = (bx + 0x7FFFu + ((bx >> 16) & 1u)) >> 16;
            by = (by + 0x7FFFu + ((by >> 16) & 1u)) >> 16;
            embbf[i] = bx | (by << 16);
        }
    }

    const int e0 = (int)blockIdx.x * SC_TILE + tid * SC_EPT;

    for (int i = tid; i < NBUCK; i += SC_THR) cnt[i] = 0;
    __syncthreads();

    int   r[SC_EPT], c[SC_EPT];
    float v[SC_EPT];
    if (e0 + SC_EPT <= n) {
        const int4* rp = (const int4*)(row + e0);
        const int4* cp = (const int4*)(col + e0);
        const float4* vp = (const float4*)(val + e0);
        #pragma unroll
        for (int q = 0; q < SC_EPT / 4; q++) {
            int4 rr = rp[q]; int4 cc = cp[q]; float4 vv = vp[q];
            r[q*4+0]=rr.x; r[q*4+1]=rr.y; r[q*4+2]=rr.z; r[q*4+3]=rr.w;
            c[q*4+0]=cc.x; c[q*4+1]=cc.y; c[q*4+2]=cc.z; c[q*4+3]=cc.w;
            v[q*4+0]=vv.x; v[q*4+1]=vv.y; v[q*4+2]=vv.z; v[q*4+3]=vv.w;
        }
    } else {
        #pragma unroll
        for (int k = 0; k < SC_EPT; k++) {
            int e = e0 + k;
            if (e < n) { r[k] = row[e]; c[k] = col[e]; v[k] = val[e]; }
            else       { r[k] = -1; }
        }
    }

    int rk[SC_EPT];
    #pragma unroll
    for (int k = 0; k < SC_EPT; k++)
        if (r[k] >= 0) rk[k] = atomicAdd(&cnt[r[k] >> RSH], 1);
    __syncthreads();

    for (int i = tid; i < NBUCK; i += SC_THR) {
        int cc = cnt[i];
        if (cc) base[i] = atomicAdd(&cursor[i], cc);
    }
    __syncthreads();

    #pragma unroll
    for (int k = 0; k < SC_EPT; k++) {
        if (r[k] >= 0) {
            int bk  = r[k] >> RSH;
            int pos = base[bk] + rk[k];
            if (pos < CAPF) {
                rec[(size_t)bk * CAPF + pos] =
                    make_int2(((r[k] & (RPB - 1)) << 17) | c[k], __float_as_int(v[k]));
            } else {
                int op = atomicAdd(ocnt, 1);
                if (op < OCAP) oflow[op] = make_int4(r[k], c[k], __float_as_int(v[k]), 0);
            }
        }
    }
}

// ---------- Phase 2a (EXPERIMENTAL): shard-phased SpMM, atomic-free ----------
// Sort by key = shard*64+row (832 keys). Wave wv's 16-row group within shard s
// is ONE contiguous run (~39 records): flat 16-deep gather batches + single
// register accumulator (records row-sorted within run), non-atomic LDS flush
// on row change. Rows exclusively owned per wave -> no races, no atomics.
template <bool BF16>
__global__ __launch_bounds__(256, 2) void spmm_shard_kernel(const int* __restrict__ fill,
                                                            const int2* __restrict__ rec,
                                                            const void* __restrict__ emb,
                                                            float* __restrict__ out)
{
    __shared__ int2  buf[CAPF];                   // 18.4 KB
    __shared__ float accx[RPB * 64];              // 16 KB
    __shared__ float accy[RPB * 64];              // 16 KB
    __shared__ int   cnt[KEYS];                   // 3.3 KB
    __shared__ int   start[KEYS];                 // 3.3 KB
    __shared__ int   sc_[KEYS];                   // 3.3 KB

    const int tid  = threadIdx.x;
    const int lane = tid & 63;
    const int wv   = tid >> 6;                    // 0..3
    const int b    = blockIdx.x;
    const int m    = min(fill[b], CAPF);
    const uint64_t* __restrict__ rec8 = (const uint64_t*)rec + (size_t)b * CAPF;
    const uint32_t* __restrict__ embu = (const uint32_t*)emb;
    const float2*   __restrict__ emb2 = (const float2*)emb;

    for (int i = tid; i < KEYS; i += 256) cnt[i] = 0;
    for (int i = tid; i < RPB * 64; i += 256) { accx[i] = 0.f; accy[i] = 0.f; }
    __syncthreads();

    // rank by key = shard*64 + row (int LDS atomics: native ds_add_rtn_u32)
    int2 rc[KMAX];
    int  rk[KMAX];
    int  ky[KMAX];
    #pragma unroll
    for (int k = 0; k < KMAX; k++) {
        int i = k * 256 + tid;
        rk[k] = -1;
        if (i < m) {
            uint64_t u = __builtin_nontemporal_load(rec8 + i);
            rc[k].x = (int)(uint32_t)u;
            rc[k].y = (int)(uint32_t)(u >> 32);
            uint32_t col = (uint32_t)rc[k].x & COLMASK;
            uint32_t rl  = (uint32_t)rc[k].x >> 17;
            ky[k] = (int)((col >> 13) * RPB + rl);               // 0..831
            rk[k] = atomicAdd(&cnt[ky[k]], 1);
        }
    }
    __syncthreads();

    // exclusive prefix scan over 832 keys (Hillis-Steele, 4 elems/thread)
    for (int i = tid; i < KEYS; i += 256) sc_[i] = cnt[i];
    __syncthreads();
    for (int off = 1; off < KEYS; off <<= 1) {
        int t[4];
        #pragma unroll
        for (int z = 0; z < 4; z++) {
            int i = tid + z * 256;
            t[z] = (i < KEYS && i >= off) ? sc_[i - off] : 0;
        }
        __syncthreads();
        #pragma unroll
        for (int z = 0; z < 4; z++) {
            int i = tid + z * 256;
            if (i < KEYS) sc_[i] += t[z];
        }
        __syncthreads();
    }
    for (int i = tid; i < KEYS; i += 256) start[i] = sc_[i] - cnt[i];
    __syncthreads();

    #pragma unroll
    for (int k = 0; k < KMAX; k++)
        if (rk[k] >= 0) buf[start[ky[k]] + rk[k]] = rc[k];
    __syncthreads();

    // shard-major sweep; wave's 16-row group = one flat run per shard
    int   cur = -1;
    float rx = 0.f, ry = 0.f;
    for (int s = 0; s < NSH; s++) {
        const int k0  = s * RPB + wv * 16;
        const int a   = start[k0];
        const int bnd = (s == NSH - 1 && wv == 3) ? m : start[k0 + 16];
        int j = a;
        for (; j + 16 <= bnd; j += 16) {          // flat 16-deep gather batch
            uint32_t u[16]; float vv[16]; int rw[16]; float2 m2[16];
            #pragma unroll
            for (int q = 0; q < 16; q++) {
                int2 e = buf[j + q];              // wave-uniform -> broadcast
                u[q]  = (((uint32_t)e.x & COLMASK) << 6) | (uint32_t)lane;
                rw[q] = (int)((uint32_t)e.x >> 17);
                vv[q] = __int_as_float(e.y);
            }
            #pragma unroll
            for (int q = 0; q < 16; q++) {
                if (BF16) u[q] = embu[u[q]]; else m2[q] = emb2[u[q]];
            }
            #pragma unroll
            for (int q = 0; q < 16; q++) {
                if (rw[q] != cur) {               // wave-uniform branch
                    if (cur >= 0) {
                        int ad = (cur << 6) | lane;
                        accx[ad] += rx; accy[ad] += ry;   // non-atomic: row owned by wave
                    }
                    cur = rw[q]; rx = 0.f; ry = 0.f;
                }
                if (BF16) {
                    rx += vv[q] * __uint_as_float(u[q] << 16);
                    ry += vv[q] * __uint_as_float(u[q] & 0xFFFF0000u);
                } else {
                    rx += vv[q] * m2[q].x; ry += vv[q] * m2[q].y;
                }
            }
        }
        for (; j + 4 <= bnd; j += 4) {
            uint32_t u[4]; float vv[4]; int rw[4]; float2 m2[4];
            #pragma unroll
            for (int q = 0; q < 4; q++) {
                int2 e = buf[j + q];
                u[q]  = (((uint32_t)e.x & COLMASK) << 6) | (uint32_t)lane;
                rw[q] = (int)((uint32_t)e.x >> 17);
                vv[q] = __int_as_float(e.y);
            }
            #pragma unroll
            for (int q = 0; q < 4; q++) {
                if (BF16) u[q] = embu[u[q]]; else m2[q] = emb2[u[q]];
            }
            #pragma unroll
            for (int q = 0; q < 4; q++) {
                if (rw[q] != cur) {
                    if (cur >= 0) {
                        int ad = (cur << 6) | lane;
                        accx[ad] += rx; accy[ad] += ry;
                    }
                    cur = rw[q]; rx = 0.f; ry = 0.f;
                }
                if (BF16) {
                    rx += vv[q] * __uint_as_float(u[q] << 16);
                    ry += vv[q] * __uint_as_float(u[q] & 0xFFFF0000u);
                } else {
                    rx += vv[q] * m2[q].x; ry += vv[q] * m2[q].y;
                }
            }
        }
        for (; j < bnd; j++) {
            int2 e = buf[j];
            uint32_t off = (((uint32_t)e.x & COLMASK) << 6) | (uint32_t)lane;
            int rwq = (int)((uint32_t)e.x >> 17);
            float vj = __int_as_float(e.y);
            if (rwq != cur) {
                if (cur >= 0) {
                    int ad = (cur << 6) | lane;
                    accx[ad] += rx; accy[ad] += ry;
                }
                cur = rwq; rx = 0.f; ry = 0.f;
            }
            if (BF16) {
                uint32_t w = embu[off];
                rx += vj * __uint_as_float(w << 16);
                ry += vj * __uint_as_float(w & 0xFFFF0000u);
            } else {
                float2 mm = emb2[off];
                rx += vj * mm.x; ry += vj * mm.y;
            }
        }
    }
    if (cur >= 0) {                               // final flush
        int ad = (cur << 6) | lane;
        accx[ad] += rx; accy[ad] += ry;
    }

    // writeout: wave wv reads ONLY its own rows -> no barrier needed
    #pragma unroll
    for (int p = 0; p < 16; p++) {
        const int rl   = wv * 16 + p;
        const int grow = b * RPB + rl;
        if (grow < N_NODES) {
            int ad = (rl << 6) | lane;
            uint64_t w = (uint64_t)__float_as_uint(accx[ad]) |
                         ((uint64_t)__float_as_uint(accy[ad]) << 32);
            __builtin_nontemporal_store(w, (uint64_t*)out + (size_t)grow * 64 + lane);
        }
    }
}

// ---------- Phase 2b (KNOWN-GOOD, round 1, 120.8us): overwrites out ----------
template <bool BF16>
__global__ __launch_bounds__(256) void spmm_fixed_kernel(const int* __restrict__ fill,
                                                         const int2* __restrict__ rec,
                                                         const void* __restrict__ emb,
                                                         float* __restrict__ out)
{
    __shared__ int2 buf[CAPF];
    __shared__ int  cnt[RPB];
    __shared__ int  start[RPB];
    __shared__ int  sc_[RPB];

    const int tid  = threadIdx.x;
    const int lane = tid & 63;
    const int wv   = tid >> 6;
    const int b    = blockIdx.x;
    const int m    = min(fill[b], CAPF);
    const uint64_t* __restrict__ rec8 = (const uint64_t*)rec + (size_t)b * CAPF;
    const uint32_t* __restrict__ embu = (const uint32_t*)emb;
    const float2*   __restrict__ emb2 = (const float2*)emb;

    if (tid < RPB) cnt[tid] = 0;
    __syncthreads();

    int2 rc[KMAX];
    int  rk[KMAX];
    #pragma unroll
    for (int k = 0; k < KMAX; k++) {
        int i = k * 256 + tid;
        if (i < m) {
            uint64_t u = __builtin_nontemporal_load(rec8 + i);
            rc[k].x = (int)(uint32_t)u;
            rc[k].y = (int)(uint32_t)(u >> 32);
            rk[k] = atomicAdd(&cnt[(uint32_t)rc[k].x >> 17], 1);
        }
    }
    __syncthreads();
    if (tid < RPB) sc_[tid] = cnt[tid];
    __syncthreads();
    for (int off = 1; off < RPB; off <<= 1) {
        int t = 0;
        if (tid < RPB && tid >= off) t = sc_[tid - off];
        __syncthreads();
        if (tid < RPB) sc_[tid] += t;
        __syncthreads();
    }
    if (tid < RPB) start[tid] = sc_[tid] - cnt[tid];
    __syncthreads();
    #pragma unroll
    for (int k = 0; k < KMAX; k++) {
        int i = k * 256 + tid;
        if (i < m) buf[start[(uint32_t)rc[k].x >> 17] + rk[k]] = rc[k];
    }
    __syncthreads();

    for (int rl = wv * 16; rl < wv * 16 + 16; rl++) {
        const int s0 = start[rl];
        const int c0 = cnt[rl];
        float ax = 0.f, ay = 0.f;
        int j = 0;
        for (; j + 16 <= c0; j += 16) {
            uint32_t u[16]; float vv[16]; float2 m2[16];
            #pragma unroll
            for (int q = 0; q < 16; q++) {
                int2 e = buf[s0 + j + q];
                u[q]  = (((uint32_t)e.x & COLMASK) << 6) | (uint32_t)lane;
                vv[q] = __int_as_float(e.y);
            }
            #pragma unroll
            for (int q = 0; q < 16; q++) {
                if (BF16) u[q] = embu[u[q]]; else m2[q] = emb2[u[q]];
            }
            #pragma unroll
            for (int q = 0; q < 16; q++) {
                if (BF16) {
                    ax += vv[q] * __uint_as_float(u[q] << 16);
                    ay += vv[q] * __uint_as_float(u[q] & 0xFFFF0000u);
                } else {
                    ax += vv[q] * m2[q].x; ay += vv[q] * m2[q].y;
                }
            }
        }
        for (; j + 4 <= c0; j += 4) {
            uint32_t u[4]; float vv[4]; float2 m2[4];
            #pragma unroll
            for (int q = 0; q < 4; q++) {
                int2 e = buf[s0 + j + q];
                u[q]  = (((uint32_t)e.x & COLMASK) << 6) | (uint32_t)lane;
                vv[q] = __int_as_float(e.y);
            }
            #pragma unroll
            for (int q = 0; q < 4; q++) {
                if (BF16) u[q] = embu[u[q]]; else m2[q] = emb2[u[q]];
            }
            #pragma unroll
            for (int q = 0; q < 4; q++) {
                if (BF16) {
                    ax += vv[q] * __uint_as_float(u[q] << 16);
                    ay += vv[q] * __uint_as_float(u[q] & 0xFFFF0000u);
                } else {
                    ax += vv[q] * m2[q].x; ay += vv[q] * m2[q].y;
                }
            }
        }
        for (; j < c0; j++) {
            int2 e = buf[s0 + j];
            uint32_t off = (((uint32_t)e.x & COLMASK) << 6) | (uint32_t)lane;
            float vv = __int_as_float(e.y);
            if (BF16) {
                uint32_t u = embu[off];
                ax += vv * __uint_as_float(u << 16);
                ay += vv * __uint_as_float(u & 0xFFFF0000u);
            } else {
                float2 mm = emb2[off];
                ax += vv * mm.x; ay += vv * mm.y;
            }
        }
        const int grow = b * RPB + rl;
        if (grow < N_NODES) {
            uint64_t w = (uint64_t)__float_as_uint(ax) | ((uint64_t)__float_as_uint(ay) << 32);
            __builtin_nontemporal_store(w, (uint64_t*)out + (size_t)grow * 64 + lane);
        }
    }
}

// ---------- Phase 3: overflow fixup ----------
__global__ __launch_bounds__(256) void oflow_kernel(const int4* __restrict__ oflow,
                                                    const int* __restrict__ ocnt,
                                                    const float* __restrict__ embeds,
                                                    float* __restrict__ out) {
    const int nof  = min(*ocnt, OCAP);
    const int lane = threadIdx.x & 63;
    const int w    = ((int)blockIdx.x * 256 + threadIdx.x) >> 6;
    const int nw   = ((int)gridDim.x * 256) >> 6;
    for (int i = w; i < nof; i += nw) {
        int4 e = oflow[i];
        const float2* src = (const float2*)(embeds + (size_t)e.y * D_FEAT);
        float2 mm = src[lane];
        float vv = __int_as_float(e.z);
        float* dst = out + (size_t)e.x * D_FEAT + (lane << 1);
        unsafeAtomicAdd(dst,     vv * mm.x);
        unsafeAtomicAdd(dst + 1, vv * mm.y);
    }
}

// ---------- Last-resort fallback ----------
__global__ __launch_bounds__(256) void spmm_atomic_kernel(
    const int* __restrict__ edge_row, const int* __restrict__ edge_col,
    const float* __restrict__ edge_val, const float* __restrict__ embeds,
    float* __restrict__ out, int n_edges)
{
    const int lane    = threadIdx.x & 63;
    const int wave_id = ((int)blockIdx.x * blockDim.x + threadIdx.x) >> 6;
    const int n_waves = ((int)gridDim.x * blockDim.x) >> 6;
    for (int e = wave_id; e < n_edges; e += n_waves) {
        const int   r = edge_row[e];
        const int   c = edge_col[e];
        const float vv = edge_val[e];
        const float2* src = (const float2*)(embeds + (size_t)c * D_FEAT);
        float2 mm = src[lane];
        float* dst = out + (size_t)r * D_FEAT + (lane << 1);
        unsafeAtomicAdd(dst,     vv * mm.x);
        unsafeAtomicAdd(dst + 1, vv * mm.y);
    }
}

static inline size_t align256(size_t x) { return (x + 255) & ~(size_t)255; }

extern "C" void kernel_launch(void* const* d_in, const int* in_sizes, int n_in,
                              void* d_out, int out_size, void* d_ws, size_t ws_size,
                              hipStream_t stream) {
    const int*   edge_row = (const int*)d_in[0];
    const int*   edge_col = (const int*)d_in[1];
    const float* edge_val = (const float*)d_in[2];
    const float* embeds   = (const float*)d_in[3];
    float*       out      = (float*)d_out;

    const int n_edges = in_sizes[0];

    size_t off = 0;
    size_t o_cursor = off; off = align256(off + (size_t)(NBUCK + 1) * 4);
    size_t o_oflow  = off; off = align256(off + (size_t)OCAP * 16);
    size_t o_rec    = off; off = align256(off + (size_t)NBUCK * CAPF * 8); // 28.8 MB
    const size_t need_fp32 = off;
    size_t o_emb    = off; off = align256(off + (size_t)N_NODES * 64 * 4); // 25.6 MB
    const size_t need_bf16 = off;

    if (ws_size < need_fp32) {
        hipMemsetAsync(out, 0, (size_t)out_size * sizeof(float), stream);
        spmm_atomic_kernel<<<dim3(4096), dim3(256), 0, stream>>>(
            edge_row, edge_col, edge_val, embeds, out, n_edges);
        return;
    }

    char* ws = (char*)d_ws;
    int*      cursor = (int*)(ws + o_cursor);
    int*      ocnt   = cursor + NBUCK;
    int4*     oflow  = (int4*)(ws + o_oflow);
    int2*     rec    = (int2*)(ws + o_rec);
    uint32_t* embbf  = (uint32_t*)(ws + o_emb);

    const bool use_bf16 = (ws_size >= need_bf16);

    hipMemsetAsync(cursor, 0, (size_t)(NBUCK + 1) * 4, stream);
    scatter_fixed_kernel<<<dim3((n_edges + SC_TILE - 1) / SC_TILE), dim3(SC_THR), 0, stream>>>(
        edge_row, edge_col, edge_val, cursor, rec, oflow, ocnt, n_edges,
        (const uint64_t*)embeds, embbf, use_bf16 ? 1 : 0);
    // A/B guard: experimental first (measured by rocprof), known-good second
    // (overwrites out -> guarantees correctness regardless of experiment).
    if (use_bf16) {
        spmm_shard_kernel<true><<<dim3(NBUCK), dim3(256), 0, stream>>>(cursor, rec, embbf, out);
        spmm_fixed_kernel<true><<<dim3(NBUCK), dim3(256), 0, stream>>>(cursor, rec, embbf, out);
    } else {
        spmm_shard_kernel<false><<<dim3(NBUCK), dim3(256), 0, stream>>>(cursor, rec, embeds, out);
        spmm_fixed_kernel<false><<<dim3(NBUCK), dim3(256), 0, stream>>>(cursor, rec, embeds, out);
    }
    oflow_kernel<<<dim3(16), dim3(256), 0, stream>>>(oflow, ocnt, embeds, out);
}

// Round 7
// 454.751 us; speedup vs baseline: 5.5634x; 1.1103x over previous
//
#include <hip/hip_runtime.h>
#include <stdint.h>

#define N_NODES 100000
#define D_FEAT  128
#define RSH     6                                 // log2(RPB)
#define RPB     64                                // rows per bucket
#define NBUCK   ((N_NODES + RPB - 1) / RPB)       // 1563
#define CAPF    2304                              // mean 2048 + 5.6 sigma
#define KMAX    ((CAPF + 255) / 256)              // 9 records/thread (256-thr spmm)
#define KMAX5   ((CAPF + 511) / 512)              // 5 records/thread (512-thr spmm)
#define NSH     13                                // column shards (col>>13), 2.1MB bf16 slice
#define KEYS    (NSH * RPB)                       // 832 sort keys
#define OCAP    8192                              // overflow list capacity
#define SC_THR  1024
#define SC_EPT  8
#define SC_TILE (SC_THR * SC_EPT)                 // 8192 edges per scatter WG
#define COLMASK 0x1FFFF

// ---------- Phase 1: single-pass batched scatter into fixed-capacity slabs ----------
// (byte-identical to rounds 2-6)
__global__ __launch_bounds__(SC_THR) void scatter_fixed_kernel(
    const int* __restrict__ row, const int* __restrict__ col,
    const float* __restrict__ val, int* __restrict__ cursor,
    int2* __restrict__ rec, int4* __restrict__ oflow, int* __restrict__ ocnt, int n,
    const uint64_t* __restrict__ embin, uint32_t* __restrict__ embbf, int do_conv)
{
    __shared__ int cnt[NBUCK];                    // 6.25 KB
    __shared__ int base[NBUCK];                   // 6.25 KB
    const int tid = threadIdx.x;

    if (do_conv) {
        const int n2 = N_NODES * (D_FEAT / 2);
        const int stride = (int)gridDim.x * SC_THR;
        for (int i = (int)blockIdx.x * SC_THR + tid; i < n2; i += stride) {
            uint64_t u = __builtin_nontemporal_load(embin + i);
            uint32_t bx = (uint32_t)u, by = (uint32_t)(u >> 32);
            bx = (bx + 0x7FFFu + ((bx >> 16) & 1u)) >> 16;
            by = (by + 0x7FFFu + ((by >> 16) & 1u)) >> 16;
            embbf[i] = bx | (by << 16);
        }
    }

    const int e0 = (int)blockIdx.x * SC_TILE + tid * SC_EPT;

    for (int i = tid; i < NBUCK; i += SC_THR) cnt[i] = 0;
    __syncthreads();

    int   r[SC_EPT], c[SC_EPT];
    float v[SC_EPT];
    if (e0 + SC_EPT <= n) {
        const int4* rp = (const int4*)(row + e0);
        const int4* cp = (const int4*)(col + e0);
        const float4* vp = (const float4*)(val + e0);
        #pragma unroll
        for (int q = 0; q < SC_EPT / 4; q++) {
            int4 rr = rp[q]; int4 cc = cp[q]; float4 vv = vp[q];
            r[q*4+0]=rr.x; r[q*4+1]=rr.y; r[q*4+2]=rr.z; r[q*4+3]=rr.w;
            c[q*4+0]=cc.x; c[q*4+1]=cc.y; c[q*4+2]=cc.z; c[q*4+3]=cc.w;
            v[q*4+0]=vv.x; v[q*4+1]=vv.y; v[q*4+2]=vv.z; v[q*4+3]=vv.w;
        }
    } else {
        #pragma unroll
        for (int k = 0; k < SC_EPT; k++) {
            int e = e0 + k;
            if (e < n) { r[k] = row[e]; c[k] = col[e]; v[k] = val[e]; }
            else       { r[k] = -1; }
        }
    }

    int rk[SC_EPT];
    #pragma unroll
    for (int k = 0; k < SC_EPT; k++)
        if (r[k] >= 0) rk[k] = atomicAdd(&cnt[r[k] >> RSH], 1);
    __syncthreads();

    for (int i = tid; i < NBUCK; i += SC_THR) {
        int cc = cnt[i];
        if (cc) base[i] = atomicAdd(&cursor[i], cc);
    }
    __syncthreads();

    #pragma unroll
    for (int k = 0; k < SC_EPT; k++) {
        if (r[k] >= 0) {
            int bk  = r[k] >> RSH;
            int pos = base[bk] + rk[k];
            if (pos < CAPF) {
                rec[(size_t)bk * CAPF + pos] =
                    make_int2(((r[k] & (RPB - 1)) << 17) | c[k], __float_as_int(v[k]));
            } else {
                int op = atomicAdd(ocnt, 1);
                if (op < OCAP) oflow[op] = make_int4(r[k], c[k], __float_as_int(v[k]), 0);
            }
        }
    }
}

// ---------- Phase 2a (EXPERIMENTAL): 512-thr shard-phased SpMM, atomic-free ----------
// Round-6 algorithm at 2x the occupancy: 8 waves x 8 rows each, 2 WG/CU ->
// 16 waves/CU (was 5.6). Sort by key=shard*64+row; wave's 8-row group within
// shard s = one contiguous run (~20 rec): flat 16-deep gather batches, cur/flush
// register accumulation, non-atomic LDS flush (rows exclusively wave-owned).
// Per-shard barrier keeps all 8 waves on the same 2.1MB L2 slice.
template <bool BF16>
__global__ __launch_bounds__(512, 4) void spmm_shard_kernel(const int* __restrict__ fill,
                                                            const int2* __restrict__ rec,
                                                            const void* __restrict__ emb,
                                                            float* __restrict__ out)
{
    __shared__ int2  buf[CAPF];                   // 18.4 KB
    __shared__ float accx[RPB * 64];              // 16 KB
    __shared__ float accy[RPB * 64];              // 16 KB
    __shared__ int   cnt[KEYS];                   // 3.3 KB
    __shared__ int   start[KEYS + 1];             // 3.3 KB (+sentinel)
    __shared__ int   sc_[KEYS];                   // 3.3 KB   => ~60.3 KB total

    const int tid  = threadIdx.x;
    const int lane = tid & 63;
    const int wv   = tid >> 6;                    // 0..7
    const int b    = blockIdx.x;
    const int m    = min(fill[b], CAPF);
    const uint64_t* __restrict__ rec8 = (const uint64_t*)rec + (size_t)b * CAPF;
    const uint32_t* __restrict__ embu = (const uint32_t*)emb;
    const float2*   __restrict__ emb2 = (const float2*)emb;

    for (int i = tid; i < KEYS; i += 512) cnt[i] = 0;
    for (int i = tid; i < RPB * 64; i += 512) { accx[i] = 0.f; accy[i] = 0.f; }
    __syncthreads();

    // rank by key = shard*64 + row (int LDS atomics: native)
    int2 rc[KMAX5];
    int  rk[KMAX5];
    int  ky[KMAX5];
    #pragma unroll
    for (int k = 0; k < KMAX5; k++) {
        int i = k * 512 + tid;
        rk[k] = -1;
        if (i < m) {
            uint64_t u = __builtin_nontemporal_load(rec8 + i);
            rc[k].x = (int)(uint32_t)u;
            rc[k].y = (int)(uint32_t)(u >> 32);
            uint32_t col = (uint32_t)rc[k].x & COLMASK;
            uint32_t rl  = (uint32_t)rc[k].x >> 17;
            ky[k] = (int)((col >> 13) * RPB + rl);               // 0..831
            rk[k] = atomicAdd(&cnt[ky[k]], 1);
        }
    }
    __syncthreads();

    // exclusive prefix scan over 832 keys (Hillis-Steele, 2 elems/thread)
    for (int i = tid; i < KEYS; i += 512) sc_[i] = cnt[i];
    __syncthreads();
    for (int off = 1; off < KEYS; off <<= 1) {
        int t[2];
        #pragma unroll
        for (int z = 0; z < 2; z++) {
            int i = tid + z * 512;
            t[z] = (i < KEYS && i >= off) ? sc_[i - off] : 0;
        }
        __syncthreads();
        #pragma unroll
        for (int z = 0; z < 2; z++) {
            int i = tid + z * 512;
            if (i < KEYS) sc_[i] += t[z];
        }
        __syncthreads();
    }
    for (int i = tid; i < KEYS; i += 512) start[i] = sc_[i] - cnt[i];
    if (tid == 0) start[KEYS] = m;                // sentinel: end of last segment
    __syncthreads();

    #pragma unroll
    for (int k = 0; k < KMAX5; k++)
        if (rk[k] >= 0) buf[start[ky[k]] + rk[k]] = rc[k];
    __syncthreads();

    // shard-major sweep; wave's 8-row group = one contiguous run per shard
    int   cur = -1;
    float rx = 0.f, ry = 0.f;
    for (int s = 0; s < NSH; s++) {
        const int k0  = s * RPB + wv * 8;
        const int a   = start[k0];
        const int bnd = start[k0 + 8];            // sentinel covers s=12,wv=7
        int j = a;
        for (; j + 16 <= bnd; j += 16) {          // flat 16-deep gather batch
            uint32_t u[16]; float vv[16]; int rw[16]; float2 m2[16];
            #pragma unroll
            for (int q = 0; q < 16; q++) {
                int2 e = buf[j + q];              // wave-uniform -> broadcast
                u[q]  = (((uint32_t)e.x & COLMASK) << 6) | (uint32_t)lane;
                rw[q] = (int)((uint32_t)e.x >> 17);
                vv[q] = __int_as_float(e.y);
            }
            #pragma unroll
            for (int q = 0; q < 16; q++) {
                if (BF16) u[q] = embu[u[q]]; else m2[q] = emb2[u[q]];
            }
            #pragma unroll
            for (int q = 0; q < 16; q++) {
                if (rw[q] != cur) {               // wave-uniform branch
                    if (cur >= 0) {
                        int ad = (cur << 6) | lane;
                        accx[ad] += rx; accy[ad] += ry;   // non-atomic: row owned by wave
                    }
                    cur = rw[q]; rx = 0.f; ry = 0.f;
                }
                if (BF16) {
                    rx += vv[q] * __uint_as_float(u[q] << 16);
                    ry += vv[q] * __uint_as_float(u[q] & 0xFFFF0000u);
                } else {
                    rx += vv[q] * m2[q].x; ry += vv[q] * m2[q].y;
                }
            }
        }
        for (; j + 4 <= bnd; j += 4) {
            uint32_t u[4]; float vv[4]; int rw[4]; float2 m2[4];
            #pragma unroll
            for (int q = 0; q < 4; q++) {
                int2 e = buf[j + q];
                u[q]  = (((uint32_t)e.x & COLMASK) << 6) | (uint32_t)lane;
                rw[q] = (int)((uint32_t)e.x >> 17);
                vv[q] = __int_as_float(e.y);
            }
            #pragma unroll
            for (int q = 0; q < 4; q++) {
                if (BF16) u[q] = embu[u[q]]; else m2[q] = emb2[u[q]];
            }
            #pragma unroll
            for (int q = 0; q < 4; q++) {
                if (rw[q] != cur) {
                    if (cur >= 0) {
                        int ad = (cur << 6) | lane;
                        accx[ad] += rx; accy[ad] += ry;
                    }
                    cur = rw[q]; rx = 0.f; ry = 0.f;
                }
                if (BF16) {
                    rx += vv[q] * __uint_as_float(u[q] << 16);
                    ry += vv[q] * __uint_as_float(u[q] & 0xFFFF0000u);
                } else {
                    rx += vv[q] * m2[q].x; ry += vv[q] * m2[q].y;
                }
            }
        }
        for (; j < bnd; j++) {
            int2 e = buf[j];
            uint32_t off = (((uint32_t)e.x & COLMASK) << 6) | (uint32_t)lane;
            int rwq = (int)((uint32_t)e.x >> 17);
            float vj = __int_as_float(e.y);
            if (rwq != cur) {
                if (cur >= 0) {
                    int ad = (cur << 6) | lane;
                    accx[ad] += rx; accy[ad] += ry;
                }
                cur = rwq; rx = 0.f; ry = 0.f;
            }
            if (BF16) {
                uint32_t w = embu[off];
                rx += vj * __uint_as_float(w << 16);
                ry += vj * __uint_as_float(w & 0xFFFF0000u);
            } else {
                float2 mm = emb2[off];
                rx += vj * mm.x; ry += vj * mm.y;
            }
        }
        __syncthreads();                          // shard lockstep (L2 slice residency)
    }
    if (cur >= 0) {                               // final flush
        int ad = (cur << 6) | lane;
        accx[ad] += rx; accy[ad] += ry;
    }

    // writeout: wave wv reads ONLY its own 8 rows -> no barrier needed
    #pragma unroll
    for (int p = 0; p < 8; p++) {
        const int rl   = wv * 8 + p;
        const int grow = b * RPB + rl;
        if (grow < N_NODES) {
            int ad = (rl << 6) | lane;
            uint64_t w = (uint64_t)__float_as_uint(accx[ad]) |
                         ((uint64_t)__float_as_uint(accy[ad]) << 32);
            __builtin_nontemporal_store(w, (uint64_t*)out + (size_t)grow * 64 + lane);
        }
    }
}

// ---------- Phase 2b (KNOWN-GOOD, round 1, 120.8us): overwrites out ----------
template <bool BF16>
__global__ __launch_bounds__(256) void spmm_fixed_kernel(const int* __restrict__ fill,
                                                         const int2* __restrict__ rec,
                                                         const void* __restrict__ emb,
                                                         float* __restrict__ out)
{
    __shared__ int2 buf[CAPF];
    __shared__ int  cnt[RPB];
    __shared__ int  start[RPB];
    __shared__ int  sc_[RPB];

    const int tid  = threadIdx.x;
    const int lane = tid & 63;
    const int wv   = tid >> 6;
    const int b    = blockIdx.x;
    const int m    = min(fill[b], CAPF);
    const uint64_t* __restrict__ rec8 = (const uint64_t*)rec + (size_t)b * CAPF;
    const uint32_t* __restrict__ embu = (const uint32_t*)emb;
    const float2*   __restrict__ emb2 = (const float2*)emb;

    if (tid < RPB) cnt[tid] = 0;
    __syncthreads();

    int2 rc[KMAX];
    int  rk[KMAX];
    #pragma unroll
    for (int k = 0; k < KMAX; k++) {
        int i = k * 256 + tid;
        if (i < m) {
            uint64_t u = __builtin_nontemporal_load(rec8 + i);
            rc[k].x = (int)(uint32_t)u;
            rc[k].y = (int)(uint32_t)(u >> 32);
            rk[k] = atomicAdd(&cnt[(uint32_t)rc[k].x >> 17], 1);
        }
    }
    __syncthreads();
    if (tid < RPB) sc_[tid] = cnt[tid];
    __syncthreads();
    for (int off = 1; off < RPB; off <<= 1) {
        int t = 0;
        if (tid < RPB && tid >= off) t = sc_[tid - off];
        __syncthreads();
        if (tid < RPB) sc_[tid] += t;
        __syncthreads();
    }
    if (tid < RPB) start[tid] = sc_[tid] - cnt[tid];
    __syncthreads();
    #pragma unroll
    for (int k = 0; k < KMAX; k++) {
        int i = k * 256 + tid;
        if (i < m) buf[start[(uint32_t)rc[k].x >> 17] + rk[k]] = rc[k];
    }
    __syncthreads();

    for (int rl = wv * 16; rl < wv * 16 + 16; rl++) {
        const int s0 = start[rl];
        const int c0 = cnt[rl];
        float ax = 0.f, ay = 0.f;
        int j = 0;
        for (; j + 16 <= c0; j += 16) {
            uint32_t u[16]; float vv[16]; float2 m2[16];
            #pragma unroll
            for (int q = 0; q < 16; q++) {
                int2 e = buf[s0 + j + q];
                u[q]  = (((uint32_t)e.x & COLMASK) << 6) | (uint32_t)lane;
                vv[q] = __int_as_float(e.y);
            }
            #pragma unroll
            for (int q = 0; q < 16; q++) {
                if (BF16) u[q] = embu[u[q]]; else m2[q] = emb2[u[q]];
            }
            #pragma unroll
            for (int q = 0; q < 16; q++) {
                if (BF16) {
                    ax += vv[q] * __uint_as_float(u[q] << 16);
                    ay += vv[q] * __uint_as_float(u[q] & 0xFFFF0000u);
                } else {
                    ax += vv[q] * m2[q].x; ay += vv[q] * m2[q].y;
                }
            }
        }
        for (; j + 4 <= c0; j += 4) {
            uint32_t u[4]; float vv[4]; float2 m2[4];
            #pragma unroll
            for (int q = 0; q < 4; q++) {
                int2 e = buf[s0 + j + q];
                u[q]  = (((uint32_t)e.x & COLMASK) << 6) | (uint32_t)lane;
                vv[q] = __int_as_float(e.y);
            }
            #pragma unroll
            for (int q = 0; q < 4; q++) {
                if (BF16) u[q] = embu[u[q]]; else m2[q] = emb2[u[q]];
            }
            #pragma unroll
            for (int q = 0; q < 4; q++) {
                if (BF16) {
                    ax += vv[q] * __uint_as_float(u[q] << 16);
                    ay += vv[q] * __uint_as_float(u[q] & 0xFFFF0000u);
                } else {
                    ax += vv[q] * m2[q].x; ay += vv[q] * m2[q].y;
                }
            }
        }
        for (; j < c0; j++) {
            int2 e = buf[s0 + j];
            uint32_t off = (((uint32_t)e.x & COLMASK) << 6) | (uint32_t)lane;
            float vv = __int_as_float(e.y);
            if (BF16) {
                uint32_t u = embu[off];
                ax += vv * __uint_as_float(u << 16);
                ay += vv * __uint_as_float(u & 0xFFFF0000u);
            } else {
                float2 mm = emb2[off];
                ax += vv * mm.x; ay += vv * mm.y;
            }
        }
        const int grow = b * RPB + rl;
        if (grow < N_NODES) {
            uint64_t w = (uint64_t)__float_as_uint(ax) | ((uint64_t)__float_as_uint(ay) << 32);
            __builtin_nontemporal_store(w, (uint64_t*)out + (size_t)grow * 64 + lane);
        }
    }
}

// ---------- Phase 3: overflow fixup ----------
__global__ __launch_bounds__(256) void oflow_kernel(const int4* __restrict__ oflow,
                                                    const int* __restrict__ ocnt,
                                                    const float* __restrict__ embeds,
                                                    float* __restrict__ out) {
    const int nof  = min(*ocnt, OCAP);
    const int lane = threadIdx.x & 63;
    const int w    = ((int)blockIdx.x * 256 + threadIdx.x) >> 6;
    const int nw   = ((int)gridDim.x * 256) >> 6;
    for (int i = w; i < nof; i += nw) {
        int4 e = oflow[i];
        const float2* src = (const float2*)(embeds + (size_t)e.y * D_FEAT);
        float2 mm = src[lane];
        float vv = __int_as_float(e.z);
        float* dst = out + (size_t)e.x * D_FEAT + (lane << 1);
        unsafeAtomicAdd(dst,     vv * mm.x);
        unsafeAtomicAdd(dst + 1, vv * mm.y);
    }
}

// ---------- Last-resort fallback ----------
__global__ __launch_bounds__(256) void spmm_atomic_kernel(
    const int* __restrict__ edge_row, const int* __restrict__ edge_col,
    const float* __restrict__ edge_val, const float* __restrict__ embeds,
    float* __restrict__ out, int n_edges)
{
    const int lane    = threadIdx.x & 63;
    const int wave_id = ((int)blockIdx.x * blockDim.x + threadIdx.x) >> 6;
    const int n_waves = ((int)gridDim.x * blockDim.x) >> 6;
    for (int e = wave_id; e < n_edges; e += n_waves) {
        const int   r = edge_row[e];
        const int   c = edge_col[e];
        const float vv = edge_val[e];
        const float2* src = (const float2*)(embeds + (size_t)c * D_FEAT);
        float2 mm = src[lane];
        float* dst = out + (size_t)r * D_FEAT + (lane << 1);
        unsafeAtomicAdd(dst,     vv * mm.x);
        unsafeAtomicAdd(dst + 1, vv * mm.y);
    }
}

static inline size_t align256(size_t x) { return (x + 255) & ~(size_t)255; }

extern "C" void kernel_launch(void* const* d_in, const int* in_sizes, int n_in,
                              void* d_out, int out_size, void* d_ws, size_t ws_size,
                              hipStream_t stream) {
    const int*   edge_row = (const int*)d_in[0];
    const int*   edge_col = (const int*)d_in[1];
    const float* edge_val = (const float*)d_in[2];
    const float* embeds   = (const float*)d_in[3];
    float*       out      = (float*)d_out;

    const int n_edges = in_sizes[0];

    size_t off = 0;
    size_t o_cursor = off; off = align256(off + (size_t)(NBUCK + 1) * 4);
    size_t o_oflow  = off; off = align256(off + (size_t)OCAP * 16);
    size_t o_rec    = off; off = align256(off + (size_t)NBUCK * CAPF * 8); // 28.8 MB
    const size_t need_fp32 = off;
    size_t o_emb    = off; off = align256(off + (size_t)N_NODES * 64 * 4); // 25.6 MB
    const size_t need_bf16 = off;

    if (ws_size < need_fp32) {
        hipMemsetAsync(out, 0, (size_t)out_size * sizeof(float), stream);
        spmm_atomic_kernel<<<dim3(4096), dim3(256), 0, stream>>>(
            edge_row, edge_col, edge_val, embeds, out, n_edges);
        return;
    }

    char* ws = (char*)d_ws;
    int*      cursor = (int*)(ws + o_cursor);
    int*      ocnt   = cursor + NBUCK;
    int4*     oflow  = (int4*)(ws + o_oflow);
    int2*     rec    = (int2*)(ws + o_rec);
    uint32_t* embbf  = (uint32_t*)(ws + o_emb);

    const bool use_bf16 = (ws_size >= need_bf16);

    hipMemsetAsync(cursor, 0, (size_t)(NBUCK + 1) * 4, stream);
    scatter_fixed_kernel<<<dim3((n_edges + SC_TILE - 1) / SC_TILE), dim3(SC_THR), 0, stream>>>(
        edge_row, edge_col, edge_val, cursor, rec, oflow, ocnt, n_edges,
        (const uint64_t*)embeds, embbf, use_bf16 ? 1 : 0);
    // A/B guard: experimental first (measured by rocprof), known-good second
    // (overwrites out -> guarantees correctness regardless of experiment).
    if (use_bf16) {
        spmm_shard_kernel<true><<<dim3(NBUCK), dim3(512), 0, stream>>>(cursor, rec, embbf, out);
        spmm_fixed_kernel<true><<<dim3(NBUCK), dim3(256), 0, stream>>>(cursor, rec, embbf, out);
    } else {
        spmm_shard_kernel<false><<<dim3(NBUCK), dim3(512), 0, stream>>>(cursor, rec, embeds, out);
        spmm_fixed_kernel<false><<<dim3(NBUCK), dim3(256), 0, stream>>>(cursor, rec, embeds, out);
    }
    oflow_kernel<<<dim3(16), dim3(256), 0, stream>>>(oflow, ocnt, embeds, out);
}

// Round 8
// 308.326 us; speedup vs baseline: 8.2054x; 1.4749x over previous
//
#include <hip/hip_runtime.h>
#include <stdint.h>

#define N_NODES 100000
#define D_FEAT  128
#define RSH     5                                 // log2(RPB)
#define RPB     32                                // rows per bucket (r0 geometry: grid 3125)
#define NBUCK   ((N_NODES + RPB - 1) / RPB)       // 3125 (exactly 100000/32)
#define CAPF    1152                              // mean 1024 + 4 sigma
#define KMAX    ((CAPF + 255) / 256)              // 5 records/thread in spmm load
#define OCAP    8192                              // overflow list capacity
#define SC_THR  1024
#define SC_EPT  8
#define SC_TILE (SC_THR * SC_EPT)                 // 8192 edges per scatter WG
#define COLMASK 0x1FFFF

// ---------- Phase 1: single-pass batched scatter into fixed-capacity slabs ----------
// Per WG: LDS-rank 8192 edges by bucket, reserve contiguous ranges with ONE
// global atomic per (wg,bucket), write batches contiguously.
// cpad: cursor stride in ints (16 = one counter per 64B L2 line -> no same-line
// atomic serialization across the ~1.1M reservation atomics; 1 = fallback).
__global__ __launch_bounds__(SC_THR) void scatter_fixed_kernel(
    const int* __restrict__ row, const int* __restrict__ col,
    const float* __restrict__ val, int* __restrict__ cursor,
    int2* __restrict__ rec, int4* __restrict__ oflow, int* __restrict__ ocnt, int n,
    const uint64_t* __restrict__ embin, uint32_t* __restrict__ embbf, int do_conv,
    int cpad)
{
    __shared__ int cnt[NBUCK];                    // 12.5 KB
    __shared__ int base[NBUCK];                   // 12.5 KB
    const int tid = threadIdx.x;

    // fused conversion: fp32 pairs -> packed bf16 (RNE), streaming nt loads
    if (do_conv) {
        const int n2 = N_NODES * (D_FEAT / 2);
        const int stride = (int)gridDim.x * SC_THR;
        for (int i = (int)blockIdx.x * SC_THR + tid; i < n2; i += stride) {
            uint64_t u = __builtin_nontemporal_load(embin + i);
            uint32_t bx = (uint32_t)u, by = (uint32_t)(u >> 32);
            bx = (bx + 0x7FFFu + ((bx >> 16) & 1u)) >> 16;
            by = (by + 0x7FFFu + ((by >> 16) & 1u)) >> 16;
            embbf[i] = bx | (by << 16);
        }
    }

    const int e0 = (int)blockIdx.x * SC_TILE + tid * SC_EPT; // 8 consecutive edges/thread

    for (int i = tid; i < NBUCK; i += SC_THR) cnt[i] = 0;
    __syncthreads();

    int   r[SC_EPT], c[SC_EPT];
    float v[SC_EPT];
    if (e0 + SC_EPT <= n) {
        const int4* rp = (const int4*)(row + e0);
        const int4* cp = (const int4*)(col + e0);
        const float4* vp = (const float4*)(val + e0);
        #pragma unroll
        for (int q = 0; q < SC_EPT / 4; q++) {
            int4 rr = rp[q]; int4 cc = cp[q]; float4 vv = vp[q];
            r[q*4+0]=rr.x; r[q*4+1]=rr.y; r[q*4+2]=rr.z; r[q*4+3]=rr.w;
            c[q*4+0]=cc.x; c[q*4+1]=cc.y; c[q*4+2]=cc.z; c[q*4+3]=cc.w;
            v[q*4+0]=vv.x; v[q*4+1]=vv.y; v[q*4+2]=vv.z; v[q*4+3]=vv.w;
        }
    } else {
        #pragma unroll
        for (int k = 0; k < SC_EPT; k++) {
            int e = e0 + k;
            if (e < n) { r[k] = row[e]; c[k] = col[e]; v[k] = val[e]; }
            else       { r[k] = -1; }
        }
    }

    int rk[SC_EPT];
    #pragma unroll
    for (int k = 0; k < SC_EPT; k++)
        if (r[k] >= 0) rk[k] = atomicAdd(&cnt[r[k] >> RSH], 1);
    __syncthreads();

    for (int i = tid; i < NBUCK; i += SC_THR) {
        int cc = cnt[i];
        if (cc) base[i] = atomicAdd(&cursor[(size_t)i * cpad], cc);
    }
    __syncthreads();

    #pragma unroll
    for (int k = 0; k < SC_EPT; k++) {
        if (r[k] >= 0) {
            int bk  = r[k] >> RSH;
            int pos = base[bk] + rk[k];
            if (pos < CAPF) {
                rec[(size_t)bk * CAPF + pos] =
                    make_int2(((r[k] & (RPB - 1)) << 17) | c[k], __float_as_int(v[k]));
            } else {
                int op = atomicAdd(ocnt, 1);
                if (op < OCAP) oflow[op] = make_int4(r[k], c[k], __float_as_int(v[k]), 0);
            }
        }
    }
}

// ---------- Phase 2: fused in-LDS row sort + SpMM, one WG (256 thr) per bucket ----------
// r0 geometry (RPB=32, grid 3125 = 1.53 occupancy rounds, measured occ 65.6%)
// + r1 code (nt uint64 rec loads, 32-bit gather offsets, 16-deep batches,
// mid-loop, nt out stores). 4 waves x 8 rows each.
template <bool BF16>
__global__ __launch_bounds__(256, 8) void spmm_fixed_kernel(const int* __restrict__ fill,
                                                            const int2* __restrict__ rec,
                                                            const void* __restrict__ emb,
                                                            float* __restrict__ out,
                                                            int cpad)
{
    __shared__ int2 buf[CAPF];                    // 9.2 KB
    __shared__ int  cnt[RPB];
    __shared__ int  start[RPB];
    __shared__ int  sc_[RPB];

    const int tid  = threadIdx.x;
    const int lane = tid & 63;
    const int wv   = tid >> 6;                    // 0..3
    const int b    = blockIdx.x;
    const int m    = min(fill[(size_t)b * cpad], CAPF);
    const uint64_t* __restrict__ rec8 = (const uint64_t*)rec + (size_t)b * CAPF;
    const uint32_t* __restrict__ embu = (const uint32_t*)emb;
    const float2*   __restrict__ emb2 = (const float2*)emb;

    if (tid < RPB) cnt[tid] = 0;
    __syncthreads();

    int2 rc[KMAX];
    int  rk[KMAX];
    #pragma unroll
    for (int k = 0; k < KMAX; k++) {
        int i = k * 256 + tid;
        if (i < m) {
            uint64_t u = __builtin_nontemporal_load(rec8 + i);   // streamed once
            rc[k].x = (int)(uint32_t)u;
            rc[k].y = (int)(uint32_t)(u >> 32);
            rk[k] = atomicAdd(&cnt[(uint32_t)rc[k].x >> 17], 1);
        }
    }
    __syncthreads();
    if (tid < RPB) sc_[tid] = cnt[tid];
    __syncthreads();
    for (int off = 1; off < RPB; off <<= 1) {
        int t = 0;
        if (tid < RPB && tid >= off) t = sc_[tid - off];
        __syncthreads();
        if (tid < RPB) sc_[tid] += t;
        __syncthreads();
    }
    if (tid < RPB) start[tid] = sc_[tid] - cnt[tid];
    __syncthreads();
    #pragma unroll
    for (int k = 0; k < KMAX; k++) {
        int i = k * 256 + tid;
        if (i < m) buf[start[(uint32_t)rc[k].x >> 17] + rk[k]] = rc[k];
    }
    __syncthreads();

    for (int rl = wv * 8; rl < wv * 8 + 8; rl++) {
        const int s0 = start[rl];
        const int c0 = cnt[rl];
        float ax = 0.f, ay = 0.f;
        int j = 0;
        for (; j + 16 <= c0; j += 16) {           // 16 gathers in flight
            uint32_t u[16]; float vv[16]; float2 m2[16];
            #pragma unroll
            for (int q = 0; q < 16; q++) {
                int2 e = buf[s0 + j + q];         // wave-uniform -> broadcast
                u[q]  = (((uint32_t)e.x & COLMASK) << 6) | (uint32_t)lane;
                vv[q] = __int_as_float(e.y);
            }
            #pragma unroll
            for (int q = 0; q < 16; q++) {
                if (BF16) u[q] = embu[u[q]]; else m2[q] = emb2[u[q]];
            }
            #pragma unroll
            for (int q = 0; q < 16; q++) {
                if (BF16) {
                    ax += vv[q] * __uint_as_float(u[q] << 16);
                    ay += vv[q] * __uint_as_float(u[q] & 0xFFFF0000u);
                } else {
                    ax += vv[q] * m2[q].x; ay += vv[q] * m2[q].y;
                }
            }
        }
        for (; j + 4 <= c0; j += 4) {             // mid loop shrinks scalar tail
            uint32_t u[4]; float vv[4]; float2 m2[4];
            #pragma unroll
            for (int q = 0; q < 4; q++) {
                int2 e = buf[s0 + j + q];
                u[q]  = (((uint32_t)e.x & COLMASK) << 6) | (uint32_t)lane;
                vv[q] = __int_as_float(e.y);
            }
            #pragma unroll
            for (int q = 0; q < 4; q++) {
                if (BF16) u[q] = embu[u[q]]; else m2[q] = emb2[u[q]];
            }
            #pragma unroll
            for (int q = 0; q < 4; q++) {
                if (BF16) {
                    ax += vv[q] * __uint_as_float(u[q] << 16);
                    ay += vv[q] * __uint_as_float(u[q] & 0xFFFF0000u);
                } else {
                    ax += vv[q] * m2[q].x; ay += vv[q] * m2[q].y;
                }
            }
        }
        for (; j < c0; j++) {
            int2 e = buf[s0 + j];
            uint32_t off = (((uint32_t)e.x & COLMASK) << 6) | (uint32_t)lane;
            float vv = __int_as_float(e.y);
            if (BF16) {
                uint32_t u = embu[off];
                ax += vv * __uint_as_float(u << 16);
                ay += vv * __uint_as_float(u & 0xFFFF0000u);
            } else {
                float2 mm = emb2[off];
                ax += vv * mm.x; ay += vv * mm.y;
            }
        }
        const int grow = b * RPB + rl;            // NBUCK*RPB = 100000 exactly
        uint64_t w = (uint64_t)__float_as_uint(ax) | ((uint64_t)__float_as_uint(ay) << 32);
        __builtin_nontemporal_store(w, (uint64_t*)out + (size_t)grow * 64 + lane);
    }
}

// ---------- Phase 3: overflow fixup (statistically ~0 edges) ----------
__global__ __launch_bounds__(256) void oflow_kernel(const int4* __restrict__ oflow,
                                                    const int* __restrict__ ocnt,
                                                    const float* __restrict__ embeds,
                                                    float* __restrict__ out) {
    const int nof  = min(*ocnt, OCAP);
    const int lane = threadIdx.x & 63;
    const int w    = ((int)blockIdx.x * 256 + threadIdx.x) >> 6;
    const int nw   = ((int)gridDim.x * 256) >> 6;
    for (int i = w; i < nof; i += nw) {
        int4 e = oflow[i];
        const float2* src = (const float2*)(embeds + (size_t)e.y * D_FEAT);
        float2 mm = src[lane];
        float vv = __int_as_float(e.z);
        float* dst = out + (size_t)e.x * D_FEAT + (lane << 1);
        unsafeAtomicAdd(dst,     vv * mm.x);
        unsafeAtomicAdd(dst + 1, vv * mm.y);
    }
}

// ---------- Last-resort fallback (ws too small): atomic scatter ----------
__global__ __launch_bounds__(256) void spmm_atomic_kernel(
    const int* __restrict__ edge_row, const int* __restrict__ edge_col,
    const float* __restrict__ edge_val, const float* __restrict__ embeds,
    float* __restrict__ out, int n_edges)
{
    const int lane    = threadIdx.x & 63;
    const int wave_id = ((int)blockIdx.x * blockDim.x + threadIdx.x) >> 6;
    const int n_waves = ((int)gridDim.x * blockDim.x) >> 6;
    for (int e = wave_id; e < n_edges; e += n_waves) {
        const int   r = edge_row[e];
        const int   c = edge_col[e];
        const float vv = edge_val[e];
        const float2* src = (const float2*)(embeds + (size_t)c * D_FEAT);
        float2 mm = src[lane];
        float* dst = out + (size_t)r * D_FEAT + (lane << 1);
        unsafeAtomicAdd(dst,     vv * mm.x);
        unsafeAtomicAdd(dst + 1, vv * mm.y);
    }
}

static inline size_t align256(size_t x) { return (x + 255) & ~(size_t)255; }

extern "C" void kernel_launch(void* const* d_in, const int* in_sizes, int n_in,
                              void* d_out, int out_size, void* d_ws, size_t ws_size,
                              hipStream_t stream) {
    const int*   edge_row = (const int*)d_in[0];
    const int*   edge_col = (const int*)d_in[1];
    const float* edge_val = (const float*)d_in[2];
    const float* embeds   = (const float*)d_in[3];
    float*       out      = (float*)d_out;

    const int n_edges = in_sizes[0];

    const size_t cur16  = align256(((size_t)NBUCK * 16 + 16) * 4);   // padded cursor + ocnt
    const size_t cur1   = align256(((size_t)NBUCK + 16) * 4);        // tight cursor + ocnt
    const size_t of_sz  = align256((size_t)OCAP * 16);
    const size_t rec_sz = align256((size_t)NBUCK * CAPF * 8);        // 28.8 MB
    const size_t emb_sz = align256((size_t)N_NODES * 64 * 4);        // 25.6 MB

    int  cpad;
    bool use_bf16;
    size_t cur_sz;
    if (ws_size >= cur16 + of_sz + rec_sz + emb_sz)      { cpad = 16; use_bf16 = true;  cur_sz = cur16; }
    else if (ws_size >= cur1 + of_sz + rec_sz + emb_sz)  { cpad = 1;  use_bf16 = true;  cur_sz = cur1;  }
    else if (ws_size >= cur1 + of_sz + rec_sz)           { cpad = 1;  use_bf16 = false; cur_sz = cur1;  }
    else {
        hipMemsetAsync(out, 0, (size_t)out_size * sizeof(float), stream);
        spmm_atomic_kernel<<<dim3(4096), dim3(256), 0, stream>>>(
            edge_row, edge_col, edge_val, embeds, out, n_edges);
        return;
    }

    char* ws = (char*)d_ws;
    int*      cursor = (int*)ws;                          // [NBUCK*cpad] fill counts
    int*      ocnt   = cursor + (size_t)NBUCK * cpad;     // own line when padded
    int4*     oflow  = (int4*)(ws + cur_sz);
    int2*     rec    = (int2*)(ws + cur_sz + of_sz);
    uint32_t* embbf  = (uint32_t*)(ws + cur_sz + of_sz + rec_sz);

    hipMemsetAsync(cursor, 0, ((size_t)NBUCK * cpad + 1) * 4, stream);
    scatter_fixed_kernel<<<dim3((n_edges + SC_TILE - 1) / SC_TILE), dim3(SC_THR), 0, stream>>>(
        edge_row, edge_col, edge_val, cursor, rec, oflow, ocnt, n_edges,
        (const uint64_t*)embeds, embbf, use_bf16 ? 1 : 0, cpad);
    if (use_bf16)
        spmm_fixed_kernel<true><<<dim3(NBUCK), dim3(256), 0, stream>>>(cursor, rec, embbf, out, cpad);
    else
        spmm_fixed_kernel<false><<<dim3(NBUCK), dim3(256), 0, stream>>>(cursor, rec, embeds, out, cpad);
    oflow_kernel<<<dim3(16), dim3(256), 0, stream>>>(oflow, ocnt, embeds, out);
}

// Round 9
// 287.611 us; speedup vs baseline: 8.7964x; 1.0720x over previous
//
#include <hip/hip_runtime.h>
#include <stdint.h>

#define N_NODES 100000
#define D_FEAT  128
#define RSH     6                                 // log2(RPB) — scatter bucket = 64 rows
#define RPB     64
#define NBUCK   ((N_NODES + RPB - 1) / RPB)       // 1563 (scatter-optimal, r1-proven)
#define CAPF    2304                              // mean 2048 + 5.6 sigma
#define KMAX    ((CAPF + 255) / 256)              // 9 records/thread in spmm slab stream
#define HROWS   32                                // rows per spmm WG (half bucket)
#define OCAP    8192                              // overflow list capacity
#define SC_THR  1024
#define SC_EPT  8
#define SC_TILE (SC_THR * SC_EPT)                 // 8192 edges per scatter WG
#define COLMASK 0x1FFFF

// ---------- Phase 1: single-pass batched scatter into fixed-capacity slabs ----------
// r1-exact structure (NBUCK=1563, EPT=8, fused conv). cpad: cursor stride in
// ints (16 = one counter per 64B line -> reservation atomics hit 1563 distinct
// lines instead of 98; 1 = tight fallback).
__global__ __launch_bounds__(SC_THR) void scatter_fixed_kernel(
    const int* __restrict__ row, const int* __restrict__ col,
    const float* __restrict__ val, int* __restrict__ cursor,
    int2* __restrict__ rec, int4* __restrict__ oflow, int* __restrict__ ocnt, int n,
    const uint64_t* __restrict__ embin, uint32_t* __restrict__ embbf, int do_conv,
    int cpad)
{
    __shared__ int cnt[NBUCK];                    // 6.25 KB
    __shared__ int base[NBUCK];                   // 6.25 KB
    const int tid = threadIdx.x;

    // fused conversion: fp32 pairs -> packed bf16 (RNE), streaming nt loads
    if (do_conv) {
        const int n2 = N_NODES * (D_FEAT / 2);
        const int stride = (int)gridDim.x * SC_THR;
        for (int i = (int)blockIdx.x * SC_THR + tid; i < n2; i += stride) {
            uint64_t u = __builtin_nontemporal_load(embin + i);
            uint32_t bx = (uint32_t)u, by = (uint32_t)(u >> 32);
            bx = (bx + 0x7FFFu + ((bx >> 16) & 1u)) >> 16;
            by = (by + 0x7FFFu + ((by >> 16) & 1u)) >> 16;
            embbf[i] = bx | (by << 16);
        }
    }

    const int e0 = (int)blockIdx.x * SC_TILE + tid * SC_EPT; // 8 consecutive edges/thread

    for (int i = tid; i < NBUCK; i += SC_THR) cnt[i] = 0;
    __syncthreads();

    int   r[SC_EPT], c[SC_EPT];
    float v[SC_EPT];
    if (e0 + SC_EPT <= n) {
        const int4* rp = (const int4*)(row + e0);
        const int4* cp = (const int4*)(col + e0);
        const float4* vp = (const float4*)(val + e0);
        #pragma unroll
        for (int q = 0; q < SC_EPT / 4; q++) {
            int4 rr = rp[q]; int4 cc = cp[q]; float4 vv = vp[q];
            r[q*4+0]=rr.x; r[q*4+1]=rr.y; r[q*4+2]=rr.z; r[q*4+3]=rr.w;
            c[q*4+0]=cc.x; c[q*4+1]=cc.y; c[q*4+2]=cc.z; c[q*4+3]=cc.w;
            v[q*4+0]=vv.x; v[q*4+1]=vv.y; v[q*4+2]=vv.z; v[q*4+3]=vv.w;
        }
    } else {
        #pragma unroll
        for (int k = 0; k < SC_EPT; k++) {
            int e = e0 + k;
            if (e < n) { r[k] = row[e]; c[k] = col[e]; v[k] = val[e]; }
            else       { r[k] = -1; }
        }
    }

    int rk[SC_EPT];
    #pragma unroll
    for (int k = 0; k < SC_EPT; k++)
        if (r[k] >= 0) rk[k] = atomicAdd(&cnt[r[k] >> RSH], 1);
    __syncthreads();

    for (int i = tid; i < NBUCK; i += SC_THR) {
        int cc = cnt[i];
        if (cc) base[i] = atomicAdd(&cursor[(size_t)i * cpad], cc);
    }
    __syncthreads();

    #pragma unroll
    for (int k = 0; k < SC_EPT; k++) {
        if (r[k] >= 0) {
            int bk  = r[k] >> RSH;
            int pos = base[bk] + rk[k];
            if (pos < CAPF) {
                rec[(size_t)bk * CAPF + pos] =
                    make_int2(((r[k] & (RPB - 1)) << 17) | c[k], __float_as_int(v[k]));
            } else {
                int op = atomicAdd(ocnt, 1);
                if (op < OCAP) oflow[op] = make_int4(r[k], c[k], __float_as_int(v[k]), 0);
            }
        }
    }
}

// ---------- Phase 2: half-bucket SpMM, 2 WGs (256 thr) per 64-row slab ----------
// Grid = 2*NBUCK = 3126 (> 2048 resident slots -> occupancy ~64%, the r8-measured
// grid-fill win) while scatter keeps its coarse NBUCK=1563 buckets. Each WG
// streams the full slab (nt; +29MB total re-read ~ +8us) and ranks only its
// 32-row half. Full-size buf: per-half records <= slab records <= CAPF, no
// overflow path needed. Hot loop: 4 waves x 8 rows, 16-deep gather batches.
template <bool BF16>
__global__ __launch_bounds__(256, 8) void spmm_fixed_kernel(const int* __restrict__ fill,
                                                            const int2* __restrict__ rec,
                                                            const void* __restrict__ emb,
                                                            float* __restrict__ out,
                                                            int cpad)
{
    __shared__ int2 buf[CAPF];                    // 18.4 KB
    __shared__ int  cnt[HROWS];
    __shared__ int  start[HROWS];
    __shared__ int  sc_[HROWS];

    const int tid  = threadIdx.x;
    const int lane = tid & 63;
    const int wv   = tid >> 6;                    // 0..3
    const int b    = blockIdx.x >> 1;             // bucket
    const int half = blockIdx.x & 1;              // 32-row half within bucket
    const int m    = min(fill[(size_t)b * cpad], CAPF);
    const uint64_t* __restrict__ rec8 = (const uint64_t*)rec + (size_t)b * CAPF;
    const uint32_t* __restrict__ embu = (const uint32_t*)emb;
    const float2*   __restrict__ emb2 = (const float2*)emb;

    if (tid < HROWS) cnt[tid] = 0;
    __syncthreads();

    int2 rc[KMAX];
    int  rk[KMAX];
    #pragma unroll
    for (int k = 0; k < KMAX; k++) {
        int i = k * 256 + tid;
        rk[k] = -1;
        if (i < m) {
            uint64_t u = __builtin_nontemporal_load(rec8 + i);   // streamed once
            rc[k].x = (int)(uint32_t)u;
            rc[k].y = (int)(uint32_t)(u >> 32);
            int rl6 = (int)((uint32_t)rc[k].x >> 17);            // 0..63
            if ((rl6 >> 5) == half)
                rk[k] = atomicAdd(&cnt[rl6 & (HROWS - 1)], 1);
        }
    }
    __syncthreads();
    if (tid < HROWS) sc_[tid] = cnt[tid];
    __syncthreads();
    for (int off = 1; off < HROWS; off <<= 1) {
        int t = 0;
        if (tid < HROWS && tid >= off) t = sc_[tid - off];
        __syncthreads();
        if (tid < HROWS) sc_[tid] += t;
        __syncthreads();
    }
    if (tid < HROWS) start[tid] = sc_[tid] - cnt[tid];
    __syncthreads();
    #pragma unroll
    for (int k = 0; k < KMAX; k++) {
        if (rk[k] >= 0)
            buf[start[((uint32_t)rc[k].x >> 17) & (HROWS - 1)] + rk[k]] = rc[k];
    }
    __syncthreads();

    for (int rl = wv * 8; rl < wv * 8 + 8; rl++) {
        const int s0 = start[rl];
        const int c0 = cnt[rl];
        float ax = 0.f, ay = 0.f;
        int j = 0;
        for (; j + 16 <= c0; j += 16) {           // 16 gathers in flight
            uint32_t u[16]; float vv[16]; float2 m2[16];
            #pragma unroll
            for (int q = 0; q < 16; q++) {
                int2 e = buf[s0 + j + q];         // wave-uniform -> broadcast
                u[q]  = (((uint32_t)e.x & COLMASK) << 6) | (uint32_t)lane;
                vv[q] = __int_as_float(e.y);
            }
            #pragma unroll
            for (int q = 0; q < 16; q++) {
                if (BF16) u[q] = embu[u[q]]; else m2[q] = emb2[u[q]];
            }
            #pragma unroll
            for (int q = 0; q < 16; q++) {
                if (BF16) {
                    ax += vv[q] * __uint_as_float(u[q] << 16);
                    ay += vv[q] * __uint_as_float(u[q] & 0xFFFF0000u);
                } else {
                    ax += vv[q] * m2[q].x; ay += vv[q] * m2[q].y;
                }
            }
        }
        for (; j + 4 <= c0; j += 4) {             // mid loop shrinks scalar tail
            uint32_t u[4]; float vv[4]; float2 m2[4];
            #pragma unroll
            for (int q = 0; q < 4; q++) {
                int2 e = buf[s0 + j + q];
                u[q]  = (((uint32_t)e.x & COLMASK) << 6) | (uint32_t)lane;
                vv[q] = __int_as_float(e.y);
            }
            #pragma unroll
            for (int q = 0; q < 4; q++) {
                if (BF16) u[q] = embu[u[q]]; else m2[q] = emb2[u[q]];
            }
            #pragma unroll
            for (int q = 0; q < 4; q++) {
                if (BF16) {
                    ax += vv[q] * __uint_as_float(u[q] << 16);
                    ay += vv[q] * __uint_as_float(u[q] & 0xFFFF0000u);
                } else {
                    ax += vv[q] * m2[q].x; ay += vv[q] * m2[q].y;
                }
            }
        }
        for (; j < c0; j++) {
            int2 e = buf[s0 + j];
            uint32_t off = (((uint32_t)e.x & COLMASK) << 6) | (uint32_t)lane;
            float vv = __int_as_float(e.y);
            if (BF16) {
                uint32_t u = embu[off];
                ax += vv * __uint_as_float(u << 16);
                ay += vv * __uint_as_float(u & 0xFFFF0000u);
            } else {
                float2 mm = emb2[off];
                ax += vv * mm.x; ay += vv * mm.y;
            }
        }
        const int grow = b * RPB + half * HROWS + rl;  // NBUCK*64 = 100032 > N_NODES
        if (grow < N_NODES) {
            uint64_t w = (uint64_t)__float_as_uint(ax) | ((uint64_t)__float_as_uint(ay) << 32);
            __builtin_nontemporal_store(w, (uint64_t*)out + (size_t)grow * 64 + lane);
        }
    }
}

// ---------- Phase 3: overflow fixup (statistically ~0 edges) ----------
__global__ __launch_bounds__(256) void oflow_kernel(const int4* __restrict__ oflow,
                                                    const int* __restrict__ ocnt,
                                                    const float* __restrict__ embeds,
                                                    float* __restrict__ out) {
    const int nof  = min(*ocnt, OCAP);
    const int lane = threadIdx.x & 63;
    const int w    = ((int)blockIdx.x * 256 + threadIdx.x) >> 6;
    const int nw   = ((int)gridDim.x * 256) >> 6;
    for (int i = w; i < nof; i += nw) {
        int4 e = oflow[i];
        const float2* src = (const float2*)(embeds + (size_t)e.y * D_FEAT);
        float2 mm = src[lane];
        float vv = __int_as_float(e.z);
        float* dst = out + (size_t)e.x * D_FEAT + (lane << 1);
        unsafeAtomicAdd(dst,     vv * mm.x);
        unsafeAtomicAdd(dst + 1, vv * mm.y);
    }
}

// ---------- Last-resort fallback (ws too small): atomic scatter ----------
__global__ __launch_bounds__(256) void spmm_atomic_kernel(
    const int* __restrict__ edge_row, const int* __restrict__ edge_col,
    const float* __restrict__ edge_val, const float* __restrict__ embeds,
    float* __restrict__ out, int n_edges)
{
    const int lane    = threadIdx.x & 63;
    const int wave_id = ((int)blockIdx.x * blockDim.x + threadIdx.x) >> 6;
    const int n_waves = ((int)gridDim.x * blockDim.x) >> 6;
    for (int e = wave_id; e < n_edges; e += n_waves) {
        const int   r = edge_row[e];
        const int   c = edge_col[e];
        const float vv = edge_val[e];
        const float2* src = (const float2*)(embeds + (size_t)c * D_FEAT);
        float2 mm = src[lane];
        float* dst = out + (size_t)r * D_FEAT + (lane << 1);
        unsafeAtomicAdd(dst,     vv * mm.x);
        unsafeAtomicAdd(dst + 1, vv * mm.y);
    }
}

static inline size_t align256(size_t x) { return (x + 255) & ~(size_t)255; }

extern "C" void kernel_launch(void* const* d_in, const int* in_sizes, int n_in,
                              void* d_out, int out_size, void* d_ws, size_t ws_size,
                              hipStream_t stream) {
    const int*   edge_row = (const int*)d_in[0];
    const int*   edge_col = (const int*)d_in[1];
    const float* edge_val = (const float*)d_in[2];
    const float* embeds   = (const float*)d_in[3];
    float*       out      = (float*)d_out;

    const int n_edges = in_sizes[0];

    const size_t cur16  = align256(((size_t)NBUCK * 16 + 16) * 4);   // padded cursor + ocnt
    const size_t cur1   = align256(((size_t)NBUCK + 16) * 4);        // tight cursor + ocnt
    const size_t of_sz  = align256((size_t)OCAP * 16);
    const size_t rec_sz = align256((size_t)NBUCK * CAPF * 8);        // 28.8 MB
    const size_t emb_sz = align256((size_t)N_NODES * 64 * 4);        // 25.6 MB

    int  cpad;
    bool use_bf16;
    size_t cur_sz;
    if (ws_size >= cur16 + of_sz + rec_sz + emb_sz)      { cpad = 16; use_bf16 = true;  cur_sz = cur16; }
    else if (ws_size >= cur1 + of_sz + rec_sz + emb_sz)  { cpad = 1;  use_bf16 = true;  cur_sz = cur1;  }
    else if (ws_size >= cur1 + of_sz + rec_sz)           { cpad = 1;  use_bf16 = false; cur_sz = cur1;  }
    else {
        hipMemsetAsync(out, 0, (size_t)out_size * sizeof(float), stream);
        spmm_atomic_kernel<<<dim3(4096), dim3(256), 0, stream>>>(
            edge_row, edge_col, edge_val, embeds, out, n_edges);
        return;
    }

    char* ws = (char*)d_ws;
    int*      cursor = (int*)ws;                          // [NBUCK*cpad] fill counts
    int*      ocnt   = cursor + (size_t)NBUCK * cpad;     // own line when padded
    int4*     oflow  = (int4*)(ws + cur_sz);
    int2*     rec    = (int2*)(ws + cur_sz + of_sz);
    uint32_t* embbf  = (uint32_t*)(ws + cur_sz + of_sz + rec_sz);

    hipMemsetAsync(cursor, 0, ((size_t)NBUCK * cpad + 1) * 4, stream);
    scatter_fixed_kernel<<<dim3((n_edges + SC_TILE - 1) / SC_TILE), dim3(SC_THR), 0, stream>>>(
        edge_row, edge_col, edge_val, cursor, rec, oflow, ocnt, n_edges,
        (const uint64_t*)embeds, embbf, use_bf16 ? 1 : 0, cpad);
    if (use_bf16)
        spmm_fixed_kernel<true><<<dim3(NBUCK * 2), dim3(256), 0, stream>>>(cursor, rec, embbf, out, cpad);
    else
        spmm_fixed_kernel<false><<<dim3(NBUCK * 2), dim3(256), 0, stream>>>(cursor, rec, embeds, out, cpad);
    oflow_kernel<<<dim3(16), dim3(256), 0, stream>>>(oflow, ocnt, embeds, out);
}